// Round 1
// baseline (148.296 us; speedup 1.0000x reference)
//
#include <hip/hip_runtime.h>
#include <math.h>

#define NB      8192
#define HLEN    200
#define DIM     128
#define AH      64
#define NITEMS  100000

typedef __attribute__((ext_vector_type(8))) short bf16x8;
typedef __attribute__((ext_vector_type(4))) float f32x4;
typedef __attribute__((ext_vector_type(4))) unsigned short u16x4;

__device__ __forceinline__ unsigned short f2bf(float f) {
  unsigned int u = __float_as_uint(f);
  u += 0x7fffu + ((u >> 16) & 1u);          // RNE to bf16
  return (unsigned short)(u >> 16);
}
__device__ __forceinline__ float bf2f(unsigned short h) {
  return __uint_as_float(((unsigned int)h) << 16);
}

// ---------------------------------------------------------------------------
// Kernel 1: item_table f32 -> bf16 (halves the dominant gather traffic) and
// w1 bottom half -> transposed bf16 [64][128] so B-fragments are contiguous.
// ---------------------------------------------------------------------------
__global__ void convert_kernel(const float* __restrict__ tbl,
                               const float* __restrict__ w1,
                               unsigned short* __restrict__ tblb,
                               unsigned short* __restrict__ w1bt) {
  const long total4 = (long)NITEMS * DIM / 4;
  const long stride = (long)gridDim.x * blockDim.x;
  const long t0 = (long)blockIdx.x * blockDim.x + threadIdx.x;
  for (long i = t0; i < total4; i += stride) {
    f32x4 v = ((const f32x4*)tbl)[i];
    u16x4 o;
    o[0] = f2bf(v[0]); o[1] = f2bf(v[1]); o[2] = f2bf(v[2]); o[3] = f2bf(v[3]);
    ((u16x4*)tblb)[i] = o;
  }
  if (t0 < (long)AH * DIM) {
    int n = (int)t0 >> 7, k = (int)t0 & 127;
    w1bt[t0] = f2bf(w1[(DIM + k) * AH + n]);   // w1bt[n][k] = w1[128+k][n]
  }
}

// ---------------------------------------------------------------------------
// Kernel 2: fused attention pooling. One wave per batch element, no LDS,
// no barriers. 13 tiles of 16 history rows, MFMA 16x16x32 bf16.
// ---------------------------------------------------------------------------
template<bool BT>
__global__ __launch_bounds__(256, 2)
void main_kernel(const int* __restrict__ user_ids,
                 const int* __restrict__ user_history,
                 const float* __restrict__ user_table,
                 const float* __restrict__ item_table,
                 const unsigned short* __restrict__ tblb,
                 const float* __restrict__ w1,
                 const unsigned short* __restrict__ w1bt,
                 const float* __restrict__ b1,
                 const float* __restrict__ w2,
                 const float* __restrict__ b2,
                 float* __restrict__ out_user) {
  const int lane = threadIdx.x & 63;
  const int wave = threadIdx.x >> 6;
  const int b = blockIdx.x * 4 + wave;
  const int m = lane & 15;          // MFMA row (A) / col (B) index
  const int g = lane >> 4;          // k-group

  const int uid = __builtin_amdgcn_readfirstlane(user_ids[b]);
  const float* urow = user_table + (long)uid * DIM;

  // ub[j] = (u @ w1_top)[j] + b1[j], computed by lane j (scalar u loads, coalesced w1)
  float upj = b1[lane];
#pragma unroll 8
  for (int d = 0; d < DIM; ++d)
    upj = fmaf(urow[d], w1[d * AH + lane], upj);

  // B fragments: b[ks][nt][j] = W1bot[k = ks*32 + g*8 + j][n = nt*16 + m]
  // Same contiguous (g,j)->k map as A fragments => any bijective map is valid.
  bf16x8 bfr[4][4];
  if constexpr (BT) {
#pragma unroll
    for (int ks = 0; ks < 4; ++ks)
#pragma unroll
      for (int nt = 0; nt < 4; ++nt)
        bfr[ks][nt] = *(const bf16x8*)(w1bt + ((nt * 16 + m) * DIM + ks * 32 + g * 8));
  } else {
#pragma unroll
    for (int ks = 0; ks < 4; ++ks)
#pragma unroll
      for (int nt = 0; nt < 4; ++nt) {
        bf16x8 bv;
#pragma unroll
        for (int j = 0; j < 8; ++j)
          bv[j] = (short)f2bf(w1[(DIM + ks * 32 + g * 8 + j) * AH + nt * 16 + m]);
        bfr[ks][nt] = bv;
      }
  }

  float ubreg[4], w2reg[4];
#pragma unroll
  for (int nt = 0; nt < 4; ++nt) {
    ubreg[nt] = __shfl(upj, nt * 16 + m);
    w2reg[nt] = w2[nt * 16 + m];
  }
  const float b2v = b2[0];

  float arep[32];                    // per-lane history_repr partials
#pragma unroll
  for (int c = 0; c < 32; ++c) arep[c] = 0.f;

  const int* hrow = user_history + (long)b * HLEN;

  for (int t = 0; t < (HLEN + 15) / 16; ++t) {
    const int row = t * 16 + m;
    const int idx = (row < HLEN) ? hrow[row] : 0;

    // A fragments: a[ks][j] = Hist[m][k = ks*32 + g*8 + j]
    bf16x8 a[4];
    if constexpr (BT) {
      const unsigned short* rp = tblb + (long)idx * DIM;
#pragma unroll
      for (int ks = 0; ks < 4; ++ks)
        a[ks] = *(const bf16x8*)(rp + ks * 32 + g * 8);
    } else {
      const float* rp = item_table + (long)idx * DIM;
#pragma unroll
      for (int ks = 0; ks < 4; ++ks) {
        f32x4 lo = *(const f32x4*)(rp + ks * 32 + g * 8);
        f32x4 hi = *(const f32x4*)(rp + ks * 32 + g * 8 + 4);
        bf16x8 av;
        av[0] = (short)f2bf(lo[0]); av[1] = (short)f2bf(lo[1]);
        av[2] = (short)f2bf(lo[2]); av[3] = (short)f2bf(lo[3]);
        av[4] = (short)f2bf(hi[0]); av[5] = (short)f2bf(hi[1]);
        av[6] = (short)f2bf(hi[2]); av[7] = (short)f2bf(hi[3]);
        a[ks] = av;
      }
    }

    // S[16x64] = Hist_tile @ W1bot ; accumulate over ks into same acc
    f32x4 acc[4];
#pragma unroll
    for (int nt = 0; nt < 4; ++nt) acc[nt] = (f32x4){0.f, 0.f, 0.f, 0.f};
#pragma unroll
    for (int ks = 0; ks < 4; ++ks)
#pragma unroll
      for (int nt = 0; nt < 4; ++nt)
        acc[nt] = __builtin_amdgcn_mfma_f32_16x16x32_bf16(a[ks], bfr[ks][nt], acc[nt], 0, 0, 0);

    // C/D layout: acc[nt][r] = S[row = g*4 + r][col = nt*16 + m]
    // attn row-sum: relu(S + ub) . w2, reduced over the 16 lanes of group g
    float sums[4];
#pragma unroll
    for (int r = 0; r < 4; ++r) {
      float s = 0.f;
#pragma unroll
      for (int nt = 0; nt < 4; ++nt) {
        float h = fmaxf(acc[nt][r] + ubreg[nt], 0.f);
        s = fmaf(h, w2reg[nt], s);
      }
      s += __shfl_xor(s, 1);
      s += __shfl_xor(s, 2);
      s += __shfl_xor(s, 4);
      s += __shfl_xor(s, 8);
      sums[r] = s;
    }
    // redistribute: this lane needs the score of row m (its A-frag row)
    const int src = ((m >> 2) << 4) + m;   // a lane in group m>>2
    float v0 = __shfl(sums[0], src);
    float v1 = __shfl(sums[1], src);
    float v2 = __shfl(sums[2], src);
    float v3 = __shfl(sums[3], src);
    const int rr = m & 3;
    float sv = (rr < 2) ? ((rr == 0) ? v0 : v1) : ((rr == 2) ? v2 : v3);
    float attw = 1.f / (1.f + __expf(-(sv + b2v)));
    if (row >= HLEN) attw = 0.f;

    // reuse A-frag registers: repr[col = ks*32 + g*8 + j] += attw * hist
#pragma unroll
    for (int ks = 0; ks < 4; ++ks)
#pragma unroll
      for (int j = 0; j < 8; ++j)
        arep[ks * 8 + j] = fmaf(attw, bf2f((unsigned short)a[ks][j]), arep[ks * 8 + j]);
  }

  // sum over the 16 row-lanes of each group, then lane m==0 of each group writes
#pragma unroll
  for (int c = 0; c < 32; ++c) {
    arep[c] += __shfl_xor(arep[c], 1);
    arep[c] += __shfl_xor(arep[c], 2);
    arep[c] += __shfl_xor(arep[c], 4);
    arep[c] += __shfl_xor(arep[c], 8);
  }
  if (m == 0) {
#pragma unroll
    for (int ks = 0; ks < 4; ++ks)
#pragma unroll
      for (int j = 0; j < 8; ++j) {
        const int col = ks * 32 + g * 8 + j;
        out_user[(long)b * DIM + col] = urow[col] + arep[ks * 8 + j];
      }
  }
}

// ---------------------------------------------------------------------------
// Kernel 3: bilinear interaction u^T FI v (exact f32 accumulate, bf16 FI in
// LDS transposed for contiguous per-thread columns) + item_emb copy.
// Block = 32 batch elements, 4 register-blocked per thread.
// ---------------------------------------------------------------------------
__global__ __launch_bounds__(256, 2)
void inter_kernel(const int* __restrict__ user_ids,
                  const int* __restrict__ item_ids,
                  const float* __restrict__ user_table,
                  const float* __restrict__ item_table,
                  const float* __restrict__ fi,
                  float* __restrict__ out_item,
                  float* __restrict__ out_inter) {
  __shared__ unsigned short fitb[DIM * 130];   // fitb[e][d] = bf16(FI[d][e]), pad 130
  __shared__ float u4[4][DIM];
  __shared__ float red[4][4];
  const int t = threadIdx.x;
  for (int i = t; i < DIM * DIM; i += 256) {
    int d = i >> 7, e = i & 127;
    fitb[e * 130 + d] = f2bf(fi[i]);
  }
  const int col = t & 127;
  const int dh = t >> 7;            // which half of d
  const int lane = t & 63;
  const int wv = t >> 6;
  const int b0 = blockIdx.x * 32;
  const unsigned short* fr = &fitb[col * 130 + dh * 64];

  for (int grp = 0; grp < 8; ++grp) {
    __syncthreads();                // also covers initial fitb staging
    for (int i = t; i < 4 * DIM; i += 256) {
      int bi = i >> 7, d = i & 127;
      u4[bi][d] = user_table[(long)user_ids[b0 + grp * 4 + bi] * DIM + d];
    }
    __syncthreads();

    float a0 = 0.f, a1 = 0.f, a2 = 0.f, a3 = 0.f;
#pragma unroll 4
    for (int d = 0; d < 64; d += 4) {
      float f0 = bf2f(fr[d]), f1 = bf2f(fr[d + 1]), f2 = bf2f(fr[d + 2]), f3 = bf2f(fr[d + 3]);
      f32x4 q0 = *(const f32x4*)&u4[0][dh * 64 + d];
      f32x4 q1 = *(const f32x4*)&u4[1][dh * 64 + d];
      f32x4 q2 = *(const f32x4*)&u4[2][dh * 64 + d];
      f32x4 q3 = *(const f32x4*)&u4[3][dh * 64 + d];
      a0 = fmaf(f0, q0[0], a0); a0 = fmaf(f1, q0[1], a0); a0 = fmaf(f2, q0[2], a0); a0 = fmaf(f3, q0[3], a0);
      a1 = fmaf(f0, q1[0], a1); a1 = fmaf(f1, q1[1], a1); a1 = fmaf(f2, q1[2], a1); a1 = fmaf(f3, q1[3], a1);
      a2 = fmaf(f0, q2[0], a2); a2 = fmaf(f1, q2[1], a2); a2 = fmaf(f2, q2[2], a2); a2 = fmaf(f3, q2[3], a2);
      a3 = fmaf(f0, q3[0], a3); a3 = fmaf(f1, q3[1], a3); a3 = fmaf(f2, q3[2], a3); a3 = fmaf(f3, q3[3], a3);
    }

    const int bb = b0 + grp * 4;
    const float vv0 = item_table[(long)item_ids[bb + 0] * DIM + col];
    const float vv1 = item_table[(long)item_ids[bb + 1] * DIM + col];
    const float vv2 = item_table[(long)item_ids[bb + 2] * DIM + col];
    const float vv3 = item_table[(long)item_ids[bb + 3] * DIM + col];
    if (dh == 0) {
      out_item[(long)(bb + 0) * DIM + col] = vv0;
      out_item[(long)(bb + 1) * DIM + col] = vv1;
      out_item[(long)(bb + 2) * DIM + col] = vv2;
      out_item[(long)(bb + 3) * DIM + col] = vv3;
    }
    float p0 = a0 * vv0, p1 = a1 * vv1, p2 = a2 * vv2, p3 = a3 * vv3;
#pragma unroll
    for (int msk = 1; msk <= 32; msk <<= 1) {
      p0 += __shfl_xor(p0, msk);
      p1 += __shfl_xor(p1, msk);
      p2 += __shfl_xor(p2, msk);
      p3 += __shfl_xor(p3, msk);
    }
    if (lane == 0) { red[wv][0] = p0; red[wv][1] = p1; red[wv][2] = p2; red[wv][3] = p3; }
    __syncthreads();
    if (t < 4)
      out_inter[bb + t] = red[0][t] + red[1][t] + red[2][t] + red[3][t];
  }
}

// ---------------------------------------------------------------------------
extern "C" void kernel_launch(void* const* d_in, const int* in_sizes, int n_in,
                              void* d_out, int out_size, void* d_ws, size_t ws_size,
                              hipStream_t stream) {
  const int*   user_ids     = (const int*)d_in[0];
  const int*   item_ids     = (const int*)d_in[1];
  const int*   user_history = (const int*)d_in[2];
  const float* user_table   = (const float*)d_in[3];
  const float* item_table   = (const float*)d_in[4];
  const float* fi           = (const float*)d_in[5];
  const float* w1           = (const float*)d_in[6];
  const float* b1           = (const float*)d_in[7];
  const float* w2           = (const float*)d_in[8];
  const float* b2           = (const float*)d_in[9];

  float* out       = (float*)d_out;
  float* out_user  = out;
  float* out_item  = out + (size_t)NB * DIM;
  float* out_inter = out + (size_t)2 * NB * DIM;

  const size_t need = (size_t)NITEMS * DIM * 2 + (size_t)AH * DIM * 2;
  if (ws_size >= need) {
    unsigned short* tblb = (unsigned short*)d_ws;
    unsigned short* w1bt = tblb + (size_t)NITEMS * DIM;
    convert_kernel<<<2048, 256, 0, stream>>>(item_table, w1, tblb, w1bt);
    main_kernel<true><<<NB / 4, 256, 0, stream>>>(user_ids, user_history, user_table,
        item_table, tblb, w1, w1bt, b1, w2, b2, out_user);
  } else {
    main_kernel<false><<<NB / 4, 256, 0, stream>>>(user_ids, user_history, user_table,
        item_table, nullptr, w1, nullptr, b1, w2, b2, out_user);
  }
  inter_kernel<<<NB / 32, 256, 0, stream>>>(user_ids, item_ids, user_table, item_table,
        fi, out_item, out_inter);
}

// Round 2
// 106.938 us; speedup vs baseline: 1.3868x; 1.3868x over previous
//
#include <hip/hip_runtime.h>
#include <math.h>

#define NB      8192
#define HLEN    200
#define DIM     128
#define AH      64
#define NITEMS  100000
#define NTILE   13

typedef __attribute__((ext_vector_type(4))) float f32x4;
typedef __attribute__((ext_vector_type(2))) float f32x2;
typedef __attribute__((ext_vector_type(4))) int   i32x4;
typedef __attribute__((ext_vector_type(8))) short bf16x8;

__device__ __forceinline__ unsigned short f2bf(float f) {
  unsigned int u = __float_as_uint(f);
  u += 0x7fffu + ((u >> 16) & 1u);
  return (unsigned short)(u >> 16);
}
__device__ __forceinline__ float bf2f(unsigned short h) {
  return __uint_as_float(((unsigned int)h) << 16);
}
__device__ __forceinline__ long pick64(const i32x4& v, int h) {
  return (long)(unsigned)v[2 * h] | ((long)(unsigned)v[2 * h + 1] << 32);
}

// ---------------------------------------------------------------------------
// Kernel 1: item_table f32 -> fp8 e4m3 (row = 128B = ONE cache line) and
// w1 -> fp8 fragments laid out exactly per-lane for MFMA (both halves).
// Layout: w1f8[((((part*4+s)*4+nt)*16+m)*4+g)*8+j] = fp8(w1[kg][n]),
//   kg = part*128 + (s>>1)*64 + g*16 + (s&1)*8 + j, n = nt*16+m.
// ---------------------------------------------------------------------------
__global__ void convert_kernel(const float* __restrict__ tbl,
                               const float* __restrict__ w1,
                               unsigned char* __restrict__ tbl8,
                               unsigned char* __restrict__ w1f8) {
  const long total4 = (long)NITEMS * DIM / 4;
  const long stride = (long)gridDim.x * blockDim.x;
  const long t0 = (long)blockIdx.x * blockDim.x + threadIdx.x;
  for (long i = t0; i < total4; i += stride) {
    f32x4 v = ((const f32x4*)tbl)[i];
    int p = __builtin_amdgcn_cvt_pk_fp8_f32(v[0], v[1], 0, false);
    p     = __builtin_amdgcn_cvt_pk_fp8_f32(v[2], v[3], p, true);
    ((int*)tbl8)[i] = p;
  }
  if (t0 < 16384) {
    int L = (int)t0;
    int j  = L & 7, gg = (L >> 3) & 3, mm = (L >> 5) & 15;
    int nt = (L >> 9) & 3, s = (L >> 11) & 3, part = (L >> 13) & 1;
    int kg = part * 128 + (s >> 1) * 64 + gg * 16 + (s & 1) * 8 + j;
    int n  = nt * 16 + mm;
    float v = w1[kg * AH + n];
    int p = __builtin_amdgcn_cvt_pk_fp8_f32(v, v, 0, false);
    w1f8[L] = (unsigned char)(p & 0xff);
  }
}

// ---------------------------------------------------------------------------
// Kernel 2: fused attention pooling, fp8 path. One wave per batch element.
// Depth-3 gather pipeline, all indices preloaded, MFMA u-projection.
// ---------------------------------------------------------------------------
__global__ __launch_bounds__(256)
void main_kernel_fp8(const int* __restrict__ user_ids,
                     const int* __restrict__ user_history,
                     const float* __restrict__ user_table,
                     const unsigned char* __restrict__ tbl8,
                     const unsigned char* __restrict__ w1f8,
                     const float* __restrict__ b1,
                     const float* __restrict__ w2,
                     const float* __restrict__ b2,
                     float* __restrict__ out_user) {
  const int lane = threadIdx.x & 63;
  const int wave = threadIdx.x >> 6;
  const int b = blockIdx.x * 4 + wave;
  const int m = lane & 15;
  const int g = lane >> 4;

  const int uid = __builtin_amdgcn_readfirstlane(user_ids[b]);
  const float* urow = user_table + (long)uid * DIM;
  const int* hrow = user_history + (long)b * HLEN;

  // ---- preload all history indices (independent loads, issued at once) ----
  int idxs[NTILE];
#pragma unroll
  for (int t = 0; t < NTILE; ++t) {
    int row = t * 16 + m;
    idxs[t] = (row < HLEN) ? hrow[row] : 0;
  }

  // ---- u -> fp8 A-fragments (same (g,byte)->k map as history rows) ----
  i32x4 uf[2];
#pragma unroll
  for (int kb = 0; kb < 2; ++kb) {
    const float* up = urow + kb * 64 + g * 16;
    f32x4 q0 = *(const f32x4*)(up + 0);
    f32x4 q1 = *(const f32x4*)(up + 4);
    f32x4 q2 = *(const f32x4*)(up + 8);
    f32x4 q3 = *(const f32x4*)(up + 12);
    i32x4 d;
    d[0] = __builtin_amdgcn_cvt_pk_fp8_f32(q0[0], q0[1], 0, false);
    d[0] = __builtin_amdgcn_cvt_pk_fp8_f32(q0[2], q0[3], d[0], true);
    d[1] = __builtin_amdgcn_cvt_pk_fp8_f32(q1[0], q1[1], 0, false);
    d[1] = __builtin_amdgcn_cvt_pk_fp8_f32(q1[2], q1[3], d[1], true);
    d[2] = __builtin_amdgcn_cvt_pk_fp8_f32(q2[0], q2[1], 0, false);
    d[2] = __builtin_amdgcn_cvt_pk_fp8_f32(q2[2], q2[3], d[2], true);
    d[3] = __builtin_amdgcn_cvt_pk_fp8_f32(q3[0], q3[1], 0, false);
    d[3] = __builtin_amdgcn_cvt_pk_fp8_f32(q3[2], q3[3], d[3], true);
    uf[kb] = d;
  }

  const unsigned char* wtop = w1f8;
  const unsigned char* wbot = w1f8 + 8192;

  // ---- u-projection via MFMA: accu[nt][*] = (u @ w1_top)[nt*16+m] ----
  f32x4 accu[4];
#pragma unroll
  for (int nt = 0; nt < 4; ++nt) accu[nt] = (f32x4){0.f, 0.f, 0.f, 0.f};
#pragma unroll
  for (int s = 0; s < 4; ++s) {
    long a_s = pick64(uf[s >> 1], s & 1);
#pragma unroll
    for (int nt = 0; nt < 4; ++nt) {
      long bf = *(const long*)(wtop + ((s * 4 + nt) * 16 + m) * 32 + g * 8);
      accu[nt] = __builtin_amdgcn_mfma_f32_16x16x32_fp8_fp8(a_s, bf, accu[nt], 0, 0, 0);
    }
  }
  float ubreg[4], w2reg[4];
#pragma unroll
  for (int nt = 0; nt < 4; ++nt) {
    ubreg[nt] = accu[nt][0] + b1[nt * 16 + m];
    w2reg[nt] = w2[nt * 16 + m];
  }
  const float b2v = b2[0];

  // ---- W1 bottom fragments, held in registers (16 x 8B) ----
  long bfr[4][4];
#pragma unroll
  for (int s = 0; s < 4; ++s)
#pragma unroll
    for (int nt = 0; nt < 4; ++nt)
      bfr[s][nt] = *(const long*)(wbot + ((s * 4 + nt) * 16 + m) * 32 + g * 8);

  float arep[32];
#pragma unroll
  for (int c = 0; c < 32; ++c) arep[c] = 0.f;

  // ---- depth-3 pipelined main loop ----
  i32x4 pa[3][2];
#define LOADT(T, BUF)                                                          \
  {                                                                            \
    const unsigned char* p_ = tbl8 + ((long)idxs[T] << 7) + g * 16;            \
    pa[BUF][0] = *(const i32x4*)p_;                                            \
    pa[BUF][1] = *(const i32x4*)(p_ + 64);                                     \
  }
  LOADT(0, 0)
  LOADT(1, 1)
#pragma unroll
  for (int t = 0; t < NTILE; ++t) {
    if (t + 2 < NTILE) LOADT(t + 2, (t + 2) % 3)
    const int cb = t % 3;

    f32x4 acc[4];
#pragma unroll
    for (int nt = 0; nt < 4; ++nt) acc[nt] = (f32x4){0.f, 0.f, 0.f, 0.f};
#pragma unroll
    for (int s = 0; s < 4; ++s) {
      long a_s = pick64(pa[cb][s >> 1], s & 1);
#pragma unroll
      for (int nt = 0; nt < 4; ++nt)
        acc[nt] = __builtin_amdgcn_mfma_f32_16x16x32_fp8_fp8(a_s, bfr[s][nt], acc[nt], 0, 0, 0);
    }

    // scores: acc[nt][r] = S[row=g*4+r][col=nt*16+m]; reduce over 16 lanes
    float sums[4];
#pragma unroll
    for (int r = 0; r < 4; ++r) {
      float s = 0.f;
#pragma unroll
      for (int nt = 0; nt < 4; ++nt) {
        float h = fmaxf(acc[nt][r] + ubreg[nt], 0.f);
        s = fmaf(h, w2reg[nt], s);
      }
      s += __shfl_xor(s, 1);
      s += __shfl_xor(s, 2);
      s += __shfl_xor(s, 4);
      s += __shfl_xor(s, 8);
      sums[r] = s;
    }
    // each lane needs the score of row m: keep sums[lane&3], one shfl
    const int q = m & 3;
    float keep = (q == 0) ? sums[0] : (q == 1) ? sums[1] : (q == 2) ? sums[2] : sums[3];
    float sv = __shfl(keep, ((m >> 2) << 4) | m);
    float attw = 1.f / (1.f + __expf(-(sv + b2v)));
    if (t * 16 + m >= HLEN) attw = 0.f;

    // attention-weighted accumulate: decode fp8 row bytes in-register
#pragma unroll
    for (int kb = 0; kb < 2; ++kb)
#pragma unroll
      for (int d = 0; d < 4; ++d) {
        f32x2 lo = __builtin_amdgcn_cvt_pk_f32_fp8(pa[cb][kb][d], false);
        f32x2 hi = __builtin_amdgcn_cvt_pk_f32_fp8(pa[cb][kb][d], true);
        const int base = kb * 16 + d * 4;
        arep[base + 0] = fmaf(attw, lo[0], arep[base + 0]);
        arep[base + 1] = fmaf(attw, lo[1], arep[base + 1]);
        arep[base + 2] = fmaf(attw, hi[0], arep[base + 2]);
        arep[base + 3] = fmaf(attw, hi[1], arep[base + 3]);
      }
  }
#undef LOADT

  // reduce over the 16 row-lanes of each group; lane m==0 writes 32 cols
#pragma unroll
  for (int c = 0; c < 32; ++c) {
    arep[c] += __shfl_xor(arep[c], 1);
    arep[c] += __shfl_xor(arep[c], 2);
    arep[c] += __shfl_xor(arep[c], 4);
    arep[c] += __shfl_xor(arep[c], 8);
  }
  if (m == 0) {
#pragma unroll
    for (int kb = 0; kb < 2; ++kb)
#pragma unroll
      for (int i4 = 0; i4 < 4; ++i4) {
        const int col = kb * 64 + g * 16 + i4 * 4;
        f32x4 uv = *(const f32x4*)(urow + col);
        f32x4 o;
#pragma unroll
        for (int qq = 0; qq < 4; ++qq) o[qq] = uv[qq] + arep[kb * 16 + i4 * 4 + qq];
        *(f32x4*)(out_user + (long)b * DIM + col) = o;
      }
  }
}

// ---------------------------------------------------------------------------
// Fallback (ws too small): round-1 bf16-inline path, f32 table reads.
// ---------------------------------------------------------------------------
__global__ __launch_bounds__(256)
void main_fallback(const int* __restrict__ user_ids,
                   const int* __restrict__ user_history,
                   const float* __restrict__ user_table,
                   const float* __restrict__ item_table,
                   const float* __restrict__ w1,
                   const float* __restrict__ b1,
                   const float* __restrict__ w2,
                   const float* __restrict__ b2,
                   float* __restrict__ out_user) {
  const int lane = threadIdx.x & 63;
  const int wave = threadIdx.x >> 6;
  const int b = blockIdx.x * 4 + wave;
  const int m = lane & 15, g = lane >> 4;
  const int uid = __builtin_amdgcn_readfirstlane(user_ids[b]);
  const float* urow = user_table + (long)uid * DIM;
  float upj = b1[lane];
#pragma unroll 8
  for (int d = 0; d < DIM; ++d) upj = fmaf(urow[d], w1[d * AH + lane], upj);
  bf16x8 bfr[4][4];
#pragma unroll
  for (int ks = 0; ks < 4; ++ks)
#pragma unroll
    for (int nt = 0; nt < 4; ++nt) {
      bf16x8 bv;
#pragma unroll
      for (int j = 0; j < 8; ++j)
        bv[j] = (short)f2bf(w1[(DIM + ks * 32 + g * 8 + j) * AH + nt * 16 + m]);
      bfr[ks][nt] = bv;
    }
  float ubreg[4], w2reg[4];
#pragma unroll
  for (int nt = 0; nt < 4; ++nt) {
    ubreg[nt] = __shfl(upj, nt * 16 + m);
    w2reg[nt] = w2[nt * 16 + m];
  }
  const float b2v = b2[0];
  float arep[32];
#pragma unroll
  for (int c = 0; c < 32; ++c) arep[c] = 0.f;
  const int* hrow = user_history + (long)b * HLEN;
  for (int t = 0; t < NTILE; ++t) {
    const int row = t * 16 + m;
    const int idx = (row < HLEN) ? hrow[row] : 0;
    bf16x8 a[4];
    const float* rp = item_table + (long)idx * DIM;
#pragma unroll
    for (int ks = 0; ks < 4; ++ks) {
      f32x4 lo = *(const f32x4*)(rp + ks * 32 + g * 8);
      f32x4 hi = *(const f32x4*)(rp + ks * 32 + g * 8 + 4);
      bf16x8 av;
      av[0] = (short)f2bf(lo[0]); av[1] = (short)f2bf(lo[1]);
      av[2] = (short)f2bf(lo[2]); av[3] = (short)f2bf(lo[3]);
      av[4] = (short)f2bf(hi[0]); av[5] = (short)f2bf(hi[1]);
      av[6] = (short)f2bf(hi[2]); av[7] = (short)f2bf(hi[3]);
      a[ks] = av;
    }
    f32x4 acc[4];
#pragma unroll
    for (int nt = 0; nt < 4; ++nt) acc[nt] = (f32x4){0.f, 0.f, 0.f, 0.f};
#pragma unroll
    for (int ks = 0; ks < 4; ++ks)
#pragma unroll
      for (int nt = 0; nt < 4; ++nt)
        acc[nt] = __builtin_amdgcn_mfma_f32_16x16x32_bf16(a[ks], bfr[ks][nt], acc[nt], 0, 0, 0);
    float sums[4];
#pragma unroll
    for (int r = 0; r < 4; ++r) {
      float s = 0.f;
#pragma unroll
      for (int nt = 0; nt < 4; ++nt) {
        float h = fmaxf(acc[nt][r] + ubreg[nt], 0.f);
        s = fmaf(h, w2reg[nt], s);
      }
      s += __shfl_xor(s, 1); s += __shfl_xor(s, 2);
      s += __shfl_xor(s, 4); s += __shfl_xor(s, 8);
      sums[r] = s;
    }
    const int q = m & 3;
    float keep = (q == 0) ? sums[0] : (q == 1) ? sums[1] : (q == 2) ? sums[2] : sums[3];
    float sv = __shfl(keep, ((m >> 2) << 4) | m);
    float attw = 1.f / (1.f + __expf(-(sv + b2v)));
    if (row >= HLEN) attw = 0.f;
#pragma unroll
    for (int ks = 0; ks < 4; ++ks)
#pragma unroll
      for (int j = 0; j < 8; ++j)
        arep[ks * 8 + j] = fmaf(attw, bf2f((unsigned short)a[ks][j]), arep[ks * 8 + j]);
  }
#pragma unroll
  for (int c = 0; c < 32; ++c) {
    arep[c] += __shfl_xor(arep[c], 1);
    arep[c] += __shfl_xor(arep[c], 2);
    arep[c] += __shfl_xor(arep[c], 4);
    arep[c] += __shfl_xor(arep[c], 8);
  }
  if (m == 0) {
#pragma unroll
    for (int ks = 0; ks < 4; ++ks)
#pragma unroll
      for (int j = 0; j < 8; ++j) {
        const int col = ks * 32 + g * 8 + j;
        out_user[(long)b * DIM + col] = urow[col] + arep[ks * 8 + j];
      }
  }
}

// ---------------------------------------------------------------------------
// Kernel 3: bilinear interaction + item_emb copy (unchanged).
// ---------------------------------------------------------------------------
__global__ __launch_bounds__(256, 2)
void inter_kernel(const int* __restrict__ user_ids,
                  const int* __restrict__ item_ids,
                  const float* __restrict__ user_table,
                  const float* __restrict__ item_table,
                  const float* __restrict__ fi,
                  float* __restrict__ out_item,
                  float* __restrict__ out_inter) {
  __shared__ unsigned short fitb[DIM * 130];
  __shared__ float u4[4][DIM];
  __shared__ float red[4][4];
  const int t = threadIdx.x;
  for (int i = t; i < DIM * DIM; i += 256) {
    int d = i >> 7, e = i & 127;
    fitb[e * 130 + d] = f2bf(fi[i]);
  }
  const int col = t & 127;
  const int dh = t >> 7;
  const int lane = t & 63;
  const int wv = t >> 6;
  const int b0 = blockIdx.x * 32;
  const unsigned short* fr = &fitb[col * 130 + dh * 64];

  for (int grp = 0; grp < 8; ++grp) {
    __syncthreads();
    for (int i = t; i < 4 * DIM; i += 256) {
      int bi = i >> 7, d = i & 127;
      u4[bi][d] = user_table[(long)user_ids[b0 + grp * 4 + bi] * DIM + d];
    }
    __syncthreads();
    float a0 = 0.f, a1 = 0.f, a2 = 0.f, a3 = 0.f;
#pragma unroll 4
    for (int d = 0; d < 64; d += 4) {
      float f0 = bf2f(fr[d]), f1 = bf2f(fr[d + 1]), f2 = bf2f(fr[d + 2]), f3 = bf2f(fr[d + 3]);
      f32x4 q0 = *(const f32x4*)&u4[0][dh * 64 + d];
      f32x4 q1 = *(const f32x4*)&u4[1][dh * 64 + d];
      f32x4 q2 = *(const f32x4*)&u4[2][dh * 64 + d];
      f32x4 q3 = *(const f32x4*)&u4[3][dh * 64 + d];
      a0 = fmaf(f0, q0[0], a0); a0 = fmaf(f1, q0[1], a0); a0 = fmaf(f2, q0[2], a0); a0 = fmaf(f3, q0[3], a0);
      a1 = fmaf(f0, q1[0], a1); a1 = fmaf(f1, q1[1], a1); a1 = fmaf(f2, q1[2], a1); a1 = fmaf(f3, q1[3], a1);
      a2 = fmaf(f0, q2[0], a2); a2 = fmaf(f1, q2[1], a2); a2 = fmaf(f2, q2[2], a2); a2 = fmaf(f3, q2[3], a2);
      a3 = fmaf(f0, q3[0], a3); a3 = fmaf(f1, q3[1], a3); a3 = fmaf(f2, q3[2], a3); a3 = fmaf(f3, q3[3], a3);
    }
    const int bb = b0 + grp * 4;
    const float vv0 = item_table[(long)item_ids[bb + 0] * DIM + col];
    const float vv1 = item_table[(long)item_ids[bb + 1] * DIM + col];
    const float vv2 = item_table[(long)item_ids[bb + 2] * DIM + col];
    const float vv3 = item_table[(long)item_ids[bb + 3] * DIM + col];
    if (dh == 0) {
      out_item[(long)(bb + 0) * DIM + col] = vv0;
      out_item[(long)(bb + 1) * DIM + col] = vv1;
      out_item[(long)(bb + 2) * DIM + col] = vv2;
      out_item[(long)(bb + 3) * DIM + col] = vv3;
    }
    float p0 = a0 * vv0, p1 = a1 * vv1, p2 = a2 * vv2, p3 = a3 * vv3;
#pragma unroll
    for (int msk = 1; msk <= 32; msk <<= 1) {
      p0 += __shfl_xor(p0, msk);
      p1 += __shfl_xor(p1, msk);
      p2 += __shfl_xor(p2, msk);
      p3 += __shfl_xor(p3, msk);
    }
    if (lane == 0) { red[wv][0] = p0; red[wv][1] = p1; red[wv][2] = p2; red[wv][3] = p3; }
    __syncthreads();
    if (t < 4)
      out_inter[bb + t] = red[0][t] + red[1][t] + red[2][t] + red[3][t];
  }
}

// ---------------------------------------------------------------------------
extern "C" void kernel_launch(void* const* d_in, const int* in_sizes, int n_in,
                              void* d_out, int out_size, void* d_ws, size_t ws_size,
                              hipStream_t stream) {
  const int*   user_ids     = (const int*)d_in[0];
  const int*   item_ids     = (const int*)d_in[1];
  const int*   user_history = (const int*)d_in[2];
  const float* user_table   = (const float*)d_in[3];
  const float* item_table   = (const float*)d_in[4];
  const float* fi           = (const float*)d_in[5];
  const float* w1           = (const float*)d_in[6];
  const float* b1           = (const float*)d_in[7];
  const float* w2           = (const float*)d_in[8];
  const float* b2           = (const float*)d_in[9];

  float* out       = (float*)d_out;
  float* out_user  = out;
  float* out_item  = out + (size_t)NB * DIM;
  float* out_inter = out + (size_t)2 * NB * DIM;

  const size_t need = (size_t)NITEMS * DIM + 16384;
  if (ws_size >= need) {
    unsigned char* tbl8 = (unsigned char*)d_ws;
    unsigned char* w1f8 = tbl8 + (size_t)NITEMS * DIM;
    convert_kernel<<<1536, 256, 0, stream>>>(item_table, w1, tbl8, w1f8);
    main_kernel_fp8<<<NB / 4, 256, 0, stream>>>(user_ids, user_history, user_table,
        tbl8, w1f8, b1, w2, b2, out_user);
  } else {
    main_fallback<<<NB / 4, 256, 0, stream>>>(user_ids, user_history, user_table,
        item_table, w1, b1, w2, b2, out_user);
  }
  inter_kernel<<<NB / 32, 256, 0, stream>>>(user_ids, item_ids, user_table, item_table,
        fi, out_item, out_inter);
}